// Round 13
// baseline (50.912 us; speedup 1.0000x reference)
//
#include <hip/hip_runtime.h>
#include <math.h>

// GCDD fused v13 = R7 (best, 48.3us) + PQ-stage row factorization (only change).
// out = u + div( phi(G)*ux, phi(G)*uy ); 3x3 Sobel cross-correlations with zero
// padding at EVERY conv stage (intermediates forced to 0 outside the domain).
//
// R12 ledger: HB=8 TLP does not pay (work x1.27 > util gain); prefetch
// restructures (R8,R9) null/negative; busy ~30-32us at 60% util. This round
// cuts issued ops: per ux/uy row compute once Dx[c]=x[c+2]-x[c],
// Sx[c]=x[c]+2x[c+1]+x[c+2], Sy[c]=y[c]+2y[c+1]+y[c+2] (30 ops, reused by 3
// P-rows); per-point derivatives collapse to uxx=Dx(t)+2Dx(m)+Dx(b),
// uxy=Sx(b)-Sx(t), uyy=Sy(b)-Sy(t) (4 ops vs 15). -36 VALU/iter (~13%).
// Extra state (+42 floats) is free at HB=16 (3 waves/SIMD needs <=170 VGPR).
// Canaries: WRITE_SIZE must stay 49152 KB (no spill), VGPR <= 170.
//
// Pipeline at iter T (band-row k <-> abs gy = gy0 + k - 3):
//   L(T):  load u band-row T -> uw[T%3], ucen[T%3]
//   UX(T): ux/uy band-row T-1 (masked at invalid cols) -> factorized
//          Dx/Sx/Sy/xc/yc[(T-1)%3]
//   PQ(T): P,Q band-row T-2 -> pre-reduced dP/eQ[(T-2)%3]:
//          dP=P[c+1]-P[c-1], eQ=Q[c-1]+2Q[c]+Q[c+1]  (P,Q inherit zeros from
//          masked xc/yc; phi finite -> no explicit PQ masks needed)
//   OUT(T): out band-row T-3 = u + (dP[r-1]+2dP[r]+dP[r+1]) + (eQ[r+1]-eQ[r-1])
// Block: 256 threads = 2 bands x 128 strips (4 cols each). Grid y = H/(2*HB).

#define HB   16
#define NROW (HB + 6)   // 22 active pipeline iterations (loop padded to 24)
#define NT   256

#define STEP(TT, S0, S1, S2) do {                                              \
    const int Tt = (TT);                                                       \
    /* residual u (band-row Tt-3, slot S0) BEFORE L overwrites it */           \
    const float ur0 = ucen[S0][0], ur1 = ucen[S0][1],                          \
                ur2 = ucen[S0][2], ur3 = ucen[S0][3];                          \
    if (Tt < NROW) {                                                           \
        /* ---- L(Tt): u band-row Tt, abs gy = gy0+Tt-3 ---- */                \
        const int gy = gy0 + Tt - 3;                                           \
        float* w = uw[S0];                                                     \
        if ((unsigned)gy < (unsigned)H) {                                      \
            const float* row = uc + (long)gy * W;                              \
            const float4 va = *(const float4*)(row + ca);                      \
            const float4 vb = *(const float4*)(row + c0);                      \
            const float4 vc = *(const float4*)(row + cc);                      \
            w[0] = inb0  ? va.x : 0.f;  w[1]  = inb1  ? va.y : 0.f;            \
            w[2] = inb2  ? va.z : 0.f;  w[3]  = inb3  ? va.w : 0.f;            \
            w[4] = vb.x;                w[5]  = vb.y;                          \
            w[6] = vb.z;                w[7]  = vb.w;                          \
            w[8] = inb8  ? vc.x : 0.f;  w[9]  = inb9  ? vc.y : 0.f;            \
            w[10] = inb10 ? vc.z : 0.f; w[11] = inb11 ? vc.w : 0.f;            \
        } else {                                                               \
            _Pragma("unroll") for (int i = 0; i < 12; ++i) w[i] = 0.f;         \
        }                                                                      \
        ucen[S0][0] = w[4]; ucen[S0][1] = w[5];                                \
        ucen[S0][2] = w[6]; ucen[S0][3] = w[7];                                \
    }                                                                          \
    if (Tt >= 2 && Tt < NROW) {                                                \
        /* ---- UX(Tt): ux/uy band-row Tt-1, abs gy = gy0+Tt-4 ---- */         \
        const int gy = gy0 + Tt - 4;                                           \
        float xr[8], yr[8];                                                    \
        if ((unsigned)gy < (unsigned)H) {                                      \
            const float* a = uw[S1];   /* row Tt-2 */                          \
            const float* m = uw[S2];   /* row Tt-1 */                          \
            const float* b = uw[S0];   /* row Tt   */                          \
            _Pragma("unroll") for (int c = 0; c < 8; ++c) {                    \
                const float A = a[c+1], B = a[c+2], C = a[c+3];                \
                const float D = m[c+1],             E = m[c+3];                \
                const float F = b[c+1], Gg = b[c+2], Hh = b[c+3];              \
                const float x = (C - A) + 2.f*(E - D) + (Hh - F);              \
                const float y = (F + 2.f*Gg + Hh) - (A + 2.f*B + C);           \
                xr[c] = mU[c+2] ? x : 0.f;                                     \
                yr[c] = mU[c+2] ? y : 0.f;                                     \
            }                                                                  \
        } else {                                                               \
            _Pragma("unroll") for (int c = 0; c < 8; ++c) { xr[c]=0.f; yr[c]=0.f; } \
        }                                                                      \
        /* row factorization (reused by 3 P-rows) */                           \
        _Pragma("unroll") for (int c = 0; c < 6; ++c) {                        \
            Dx[S2][c] = xr[c+2] - xr[c];                                       \
            Sx[S2][c] = xr[c] + 2.f*xr[c+1] + xr[c+2];                         \
            Sy[S2][c] = yr[c] + 2.f*yr[c+1] + yr[c+2];                         \
            xc[S2][c] = xr[c+1];                                               \
            yc[S2][c] = yr[c+1];                                               \
        }                                                                      \
    }                                                                          \
    if (Tt >= 4 && Tt < NROW) {                                                \
        /* ---- PQ(Tt): P band-row Tt-2, abs gy = gy0+Tt-5 ---- */             \
        float* dp = dP[S1]; float* eq = eQ[S1];                                \
        const int gy = gy0 + Tt - 5;                                           \
        if ((unsigned)gy < (unsigned)H) {                                      \
            /* ux rows: Tt-3 -> S0 (top), Tt-2 -> S1 (mid), Tt-1 -> S2 (bot) */ \
            float P[6], Q[6];                                                  \
            _Pragma("unroll") for (int c = 0; c < 6; ++c) {                    \
                const float xc_ = xc[S1][c], yc_ = yc[S1][c];                  \
                const float uxx = Dx[S0][c] + 2.f*Dx[S1][c] + Dx[S2][c];       \
                const float uxy = Sx[S2][c] - Sx[S0][c];                       \
                const float uyy = Sy[S2][c] - Sy[S0][c];                       \
                const float den = 1.f + xc_*xc_ + yc_*yc_;                     \
                const float Gv = (uxx*uyy - uxy*uxy)                           \
                               * __builtin_amdgcn_rcpf(den*den + 1e-6f);       \
                const float phi = __expf(-fabsf(Gv));                          \
                /* xc_,yc_ already 0 at invalid cols; phi finite -> P,Q = 0 */ \
                P[c] = phi * xc_;                                              \
                Q[c] = phi * yc_;                                              \
            }                                                                  \
            dp[0] = P[2]-P[0]; dp[1] = P[3]-P[1];                              \
            dp[2] = P[4]-P[2]; dp[3] = P[5]-P[3];                              \
            eq[0] = Q[0]+2.f*Q[1]+Q[2]; eq[1] = Q[1]+2.f*Q[2]+Q[3];            \
            eq[2] = Q[2]+2.f*Q[3]+Q[4]; eq[3] = Q[3]+2.f*Q[4]+Q[5];            \
        } else {                                                               \
            _Pragma("unroll") for (int c = 0; c < 4; ++c) { dp[c]=0.f; eq[c]=0.f; } \
        }                                                                      \
    }                                                                          \
    if (Tt >= 6 && Tt < NROW) {                                                \
        /* ---- OUT(Tt): out band-row Tt-3, abs gy = gy0+Tt-6 (in-domain) ---- */ \
        /* P rows: gy-1 -> S2 (w1), gy -> S0 (w2), gy+1 -> S1 (w1) */          \
        const float o0 = ur0 + (dP[S2][0] + 2.f*dP[S0][0] + dP[S1][0])         \
                             + (eQ[S1][0] - eQ[S2][0]);                        \
        const float o1 = ur1 + (dP[S2][1] + 2.f*dP[S0][1] + dP[S1][1])         \
                             + (eQ[S1][1] - eQ[S2][1]);                        \
        const float o2 = ur2 + (dP[S2][2] + 2.f*dP[S0][2] + dP[S1][2])         \
                             + (eQ[S1][2] - eQ[S2][2]);                        \
        const float o3 = ur3 + (dP[S2][3] + 2.f*dP[S0][3] + dP[S1][3])         \
                             + (eQ[S1][3] - eQ[S2][3]);                        \
        *(float4*)(oc + (long)(gy0 + Tt - 6) * W + c0) =                       \
            make_float4(o0, o1, o2, o3);                                       \
    }                                                                          \
} while (0)

__global__ __launch_bounds__(NT) void gcdd_sweep(
    const float* __restrict__ u, float* __restrict__ out, int H, int W)
{
    const int tid   = threadIdx.x;
    const int strip = tid & 127;          // 128 strips x 4 cols = W = 512
    const int band  = tid >> 7;           // 2 bands per block (wave-uniform)
    const int c0    = strip * 4;
    const int gy0   = (blockIdx.y * 2 + band) * HB;
    const long chan = blockIdx.z;
    const float* __restrict__ uc = u + chan * (long)H * W;
    float* __restrict__ oc = out + chan * (long)H * W;

    // Clamped load-base cols (keeps addresses in-bounds; clamped-in values are
    // masked to zero below, implementing the zero-padding of the first conv).
    const int ca = (c0 - 4 < 0) ? 0 : (c0 - 4);
    const int cc = (c0 + 4 > W - 4) ? (W - 4) : (c0 + 4);

    // uw[i] holds u col c0-4+i; validity masks (only edge strips have false).
    bool mU[12];
    #pragma unroll
    for (int i = 0; i < 12; ++i)
        mU[i] = (unsigned)(c0 - 4 + i) < (unsigned)W;
    const bool inb0 = mU[0], inb1 = mU[1], inb2 = mU[2], inb3 = mU[3];
    const bool inb8 = mU[8], inb9 = mU[9], inb10 = mU[10], inb11 = mU[11];

    float uw[3][12];
    float ucen[3][4] = {};
    float Dx[3][6], Sx[3][6], Sy[3][6], xc[3][6], yc[3][6];
    float dP[3][4], eQ[3][4];

    // 24 iterations (22 active), 3x-unrolled: all slot indices literal.
    for (int t = 0; t < NROW + 2; t += 3) {
        STEP(t + 0, 0, 1, 2);
        STEP(t + 1, 1, 2, 0);
        STEP(t + 2, 2, 0, 1);
    }
}

extern "C" void kernel_launch(void* const* d_in, const int* in_sizes, int n_in,
                              void* d_out, int out_size, void* d_ws, size_t ws_size,
                              hipStream_t stream) {
    const float* u = (const float*)d_in[0];
    float* out = (float*)d_out;

    const int H = 512, W = 512;
    const int channels = in_sizes[0] / (H * W);  // B*C = 48

    dim3 grid(1, H / (2 * HB), channels);        // 1 x 16 x 48 = 768 blocks
    dim3 block(NT);
    gcdd_sweep<<<grid, block, 0, stream>>>(u, out, H, W);
}

// Round 14
// 49.292 us; speedup vs baseline: 1.0328x; 1.0328x over previous
//
#include <hip/hip_runtime.h>
#include <math.h>

// GCDD fused v14 = R7 structure + BOTH factorization levels (Du/Su at u level,
// Dx/Sx/Sy at ux level). Load placement is R7-byte-identical (load row T,
// consume in the same iteration — the only ordering that measured fastest;
// prefetch variants R8/R9 were null/negative).
// out = u + div( phi(G)*ux, phi(G)*uy ); 3x3 Sobel cross-correlations with zero
// padding at EVERY conv stage (intermediates forced to 0 outside the domain).
//
// Ledger: wall = VALU-busy + ~20us stall (resists prefetch/TLP/op-cuts).
// This round minimizes busy: per u row Du[c]=u[c+3]-u[c+1], Su[c]=u[c+1]+
// 2u[c+2]+u[c+3] (reused by 3 ux rows); ux=Du(t)+2Du(m)+Du(b), uy=Su(b)-Su(t).
// Per ux row Dx[c]=x[c+2]-x[c], Sx=x+2x+x, Sy=y+2y+y (reused by 3 P rows);
// uxx=Dx(t)+2Dx(m)+Dx(b), uxy=Sx(b)-Sx(t), uyy=Sy(b)-Sy(t).
// ~306 core ops/iter vs R7's measured ~520.
// Masks: u zeroed at load (inb*); ux/uy masked at out-of-domain cols (mU);
// P,Q inherit zeros (phi finite). Canaries: WRITE_SIZE==49152 KB, VGPR<=140.
//
// Pipeline at iter T (band-row k <-> abs gy = gy0 + k - 3):
//   L(T):  load u band-row T -> Du/Su/ucen[T%3]
//   UX(T): ux/uy band-row T-1 -> Dx/Sx/Sy/xc/yc[(T-1)%3]
//   PQ(T): P,Q band-row T-2 -> pre-reduced dP/eQ[(T-2)%3]:
//          dP=P[c+1]-P[c-1], eQ=Q[c-1]+2Q[c]+Q[c+1]
//   OUT(T): out band-row T-3 = u + (dP[r-1]+2dP[r]+dP[r+1]) + (eQ[r+1]-eQ[r-1])
// Block: 256 threads = 2 bands x 128 strips (4 cols each). Grid y = H/(2*HB).

#define HB   16
#define NROW (HB + 6)   // 22 active pipeline iterations (loop padded to 24)
#define NT   256

#define STEP(TT, S0, S1, S2) do {                                              \
    const int Tt = (TT);                                                       \
    /* residual u (band-row Tt-3, slot S0) BEFORE L overwrites it */           \
    const float ur0 = ucen[S0][0], ur1 = ucen[S0][1],                          \
                ur2 = ucen[S0][2], ur3 = ucen[S0][3];                          \
    if (Tt < NROW) {                                                           \
        /* ---- L(Tt): u band-row Tt, abs gy = gy0+Tt-3 -> Du/Su/ucen[S0] ---- */ \
        const int gy = gy0 + Tt - 3;                                           \
        float w[12];                                                           \
        if ((unsigned)gy < (unsigned)H) {                                      \
            const float* row = uc + (long)gy * W;                              \
            const float4 va = *(const float4*)(row + ca);                      \
            const float4 vb = *(const float4*)(row + c0);                      \
            const float4 vc = *(const float4*)(row + cc);                      \
            w[0] = inb0  ? va.x : 0.f;  w[1]  = inb1  ? va.y : 0.f;            \
            w[2] = inb2  ? va.z : 0.f;  w[3]  = inb3  ? va.w : 0.f;            \
            w[4] = vb.x;                w[5]  = vb.y;                          \
            w[6] = vb.z;                w[7]  = vb.w;                          \
            w[8] = inb8  ? vc.x : 0.f;  w[9]  = inb9  ? vc.y : 0.f;            \
            w[10] = inb10 ? vc.z : 0.f; w[11] = inb11 ? vc.w : 0.f;            \
        } else {                                                               \
            _Pragma("unroll") for (int i = 0; i < 12; ++i) w[i] = 0.f;         \
        }                                                                      \
        _Pragma("unroll") for (int c = 0; c < 8; ++c) {                        \
            Du[S0][c] = w[c+3] - w[c+1];                                       \
            Su[S0][c] = w[c+1] + 2.f*w[c+2] + w[c+3];                          \
        }                                                                      \
        ucen[S0][0] = w[4]; ucen[S0][1] = w[5];                                \
        ucen[S0][2] = w[6]; ucen[S0][3] = w[7];                                \
    }                                                                          \
    if (Tt >= 2 && Tt < NROW) {                                                \
        /* ---- UX(Tt): ux/uy band-row Tt-1, abs gy = gy0+Tt-4 ---- */         \
        /* u rows: Tt-2 -> S1, Tt-1 -> S2, Tt -> S0 */                         \
        const int gy = gy0 + Tt - 4;                                           \
        float xr[8], yr[8];                                                    \
        if ((unsigned)gy < (unsigned)H) {                                      \
            _Pragma("unroll") for (int c = 0; c < 8; ++c) {                    \
                const float x = Du[S1][c] + 2.f*Du[S2][c] + Du[S0][c];         \
                const float y = Su[S0][c] - Su[S1][c];                         \
                xr[c] = mU[c+2] ? x : 0.f;                                     \
                yr[c] = mU[c+2] ? y : 0.f;                                     \
            }                                                                  \
        } else {                                                               \
            _Pragma("unroll") for (int c = 0; c < 8; ++c) { xr[c]=0.f; yr[c]=0.f; } \
        }                                                                      \
        /* level-2 row factorization (reused by 3 P-rows), stored at slot S2 */ \
        _Pragma("unroll") for (int c = 0; c < 6; ++c) {                        \
            Dx[S2][c] = xr[c+2] - xr[c];                                       \
            Sx[S2][c] = xr[c] + 2.f*xr[c+1] + xr[c+2];                         \
            Sy[S2][c] = yr[c] + 2.f*yr[c+1] + yr[c+2];                         \
            xc[S2][c] = xr[c+1];                                               \
            yc[S2][c] = yr[c+1];                                               \
        }                                                                      \
    }                                                                          \
    if (Tt >= 4 && Tt < NROW) {                                                \
        /* ---- PQ(Tt): P band-row Tt-2, abs gy = gy0+Tt-5 ---- */             \
        float* dp = dP[S1]; float* eq = eQ[S1];                                \
        const int gy = gy0 + Tt - 5;                                           \
        if ((unsigned)gy < (unsigned)H) {                                      \
            /* ux rows: Tt-3 -> S0 (top), Tt-2 -> S1 (mid), Tt-1 -> S2 (bot) */ \
            float P[6], Q[6];                                                  \
            _Pragma("unroll") for (int c = 0; c < 6; ++c) {                    \
                const float xc_ = xc[S1][c], yc_ = yc[S1][c];                  \
                const float uxx = Dx[S0][c] + 2.f*Dx[S1][c] + Dx[S2][c];       \
                const float uxy = Sx[S2][c] - Sx[S0][c];                       \
                const float uyy = Sy[S2][c] - Sy[S0][c];                       \
                const float den = 1.f + xc_*xc_ + yc_*yc_;                     \
                const float Gv = (uxx*uyy - uxy*uxy)                           \
                               * __builtin_amdgcn_rcpf(den*den + 1e-6f);       \
                const float phi = __expf(-fabsf(Gv));                          \
                /* xc_,yc_ already 0 at invalid cols; phi finite -> P,Q = 0 */ \
                P[c] = phi * xc_;                                              \
                Q[c] = phi * yc_;                                              \
            }                                                                  \
            dp[0] = P[2]-P[0]; dp[1] = P[3]-P[1];                              \
            dp[2] = P[4]-P[2]; dp[3] = P[5]-P[3];                              \
            eq[0] = Q[0]+2.f*Q[1]+Q[2]; eq[1] = Q[1]+2.f*Q[2]+Q[3];            \
            eq[2] = Q[2]+2.f*Q[3]+Q[4]; eq[3] = Q[3]+2.f*Q[4]+Q[5];            \
        } else {                                                               \
            _Pragma("unroll") for (int c = 0; c < 4; ++c) { dp[c]=0.f; eq[c]=0.f; } \
        }                                                                      \
    }                                                                          \
    if (Tt >= 6 && Tt < NROW) {                                                \
        /* ---- OUT(Tt): out band-row Tt-3, abs gy = gy0+Tt-6 (in-domain) ---- */ \
        /* P rows: gy-1 -> S2 (w1), gy -> S0 (w2), gy+1 -> S1 (w1) */          \
        const float o0 = ur0 + (dP[S2][0] + 2.f*dP[S0][0] + dP[S1][0])         \
                             + (eQ[S1][0] - eQ[S2][0]);                        \
        const float o1 = ur1 + (dP[S2][1] + 2.f*dP[S0][1] + dP[S1][1])         \
                             + (eQ[S1][1] - eQ[S2][1]);                        \
        const float o2 = ur2 + (dP[S2][2] + 2.f*dP[S0][2] + dP[S1][2])         \
                             + (eQ[S1][2] - eQ[S2][2]);                        \
        const float o3 = ur3 + (dP[S2][3] + 2.f*dP[S0][3] + dP[S1][3])         \
                             + (eQ[S1][3] - eQ[S2][3]);                        \
        *(float4*)(oc + (long)(gy0 + Tt - 6) * W + c0) =                       \
            make_float4(o0, o1, o2, o3);                                       \
    }                                                                          \
} while (0)

__global__ __launch_bounds__(NT) void gcdd_sweep(
    const float* __restrict__ u, float* __restrict__ out, int H, int W)
{
    const int tid   = threadIdx.x;
    const int strip = tid & 127;          // 128 strips x 4 cols = W = 512
    const int band  = tid >> 7;           // 2 bands per block (wave-uniform)
    const int c0    = strip * 4;
    const int gy0   = (blockIdx.y * 2 + band) * HB;
    const long chan = blockIdx.z;
    const float* __restrict__ uc = u + chan * (long)H * W;
    float* __restrict__ oc = out + chan * (long)H * W;

    // Clamped load-base cols (keeps addresses in-bounds; clamped-in values are
    // masked to zero below, implementing the zero-padding of the first conv).
    const int ca = (c0 - 4 < 0) ? 0 : (c0 - 4);
    const int cc = (c0 + 4 > W - 4) ? (W - 4) : (c0 + 4);

    // col validity for u cols c0-4+i; only edge strips have false entries.
    bool mU[12];
    #pragma unroll
    for (int i = 0; i < 12; ++i)
        mU[i] = (unsigned)(c0 - 4 + i) < (unsigned)W;
    const bool inb0 = mU[0], inb1 = mU[1], inb2 = mU[2], inb3 = mU[3];
    const bool inb8 = mU[8], inb9 = mU[9], inb10 = mU[10], inb11 = mU[11];

    float Du[3][8], Su[3][8];
    float ucen[3][4] = {};
    float Dx[3][6], Sx[3][6], Sy[3][6], xc[3][6], yc[3][6];
    float dP[3][4], eQ[3][4];

    // 24 iterations (22 active), 3x-unrolled: all slot indices literal.
    for (int t = 0; t < NROW + 2; t += 3) {
        STEP(t + 0, 0, 1, 2);
        STEP(t + 1, 1, 2, 0);
        STEP(t + 2, 2, 0, 1);
    }
}

extern "C" void kernel_launch(void* const* d_in, const int* in_sizes, int n_in,
                              void* d_out, int out_size, void* d_ws, size_t ws_size,
                              hipStream_t stream) {
    const float* u = (const float*)d_in[0];
    float* out = (float*)d_out;

    const int H = 512, W = 512;
    const int channels = in_sizes[0] / (H * W);  // B*C = 48

    dim3 grid(1, H / (2 * HB), channels);        // 1 x 16 x 48 = 768 blocks
    dim3 block(NT);
    gcdd_sweep<<<grid, block, 0, stream>>>(u, out, H, W);
}

// Round 15
// 47.643 us; speedup vs baseline: 1.0686x; 1.0346x over previous
//
#include <hip/hip_runtime.h>
#include <math.h>

// GCDD fused v15 = R7 byte-identical pipeline + per-block s_sleep stagger.
// out = u + div( phi(G)*ux, phi(G)*uy ); 3x3 Sobel cross-correlations with zero
// padding at EVERY conv stage (intermediates forced to 0 outside the domain).
//
// Ledger (R7..R14): VALU-busy pinned at ~30us across ALL source variants
// (compiler CSEs every factorization); stall ~20us resists prefetch (R8,R9),
// 2x TLP (R12: busy 59->65% only), op cuts (R13,R14). Hypothesis: co-resident
// waves are PHASE-LOCKED (identical code, simultaneous start) -> load bursts
// coincide, TLP can't interleave. Probe: stagger block start by
// (flat block id % 4) * ~256 cycles via s_sleep. If busy% doesn't rise,
// phase-lock is refuted and R7 is the structural floor.
//
// Pipeline at iter T (band-row k <-> abs gy = gy0 + k - 3):
//   L(T):  load u band-row T -> uw[T%3], ucen[T%3]
//   UX(T): ux/uy band-row T-1 -> xw/yw[(T-1)%3]   (masked at invalid cols)
//   PQ(T): P,Q band-row T-2 -> pre-reduced dP/eQ[(T-2)%3]:
//          dP=P[c+1]-P[c-1], eQ=Q[c-1]+2Q[c]+Q[c+1]
//   OUT(T): out band-row T-3 = u + (dP[r-1]+2dP[r]+dP[r+1]) + (eQ[r+1]-eQ[r-1])
// Block: 256 threads = 2 bands x 128 strips (4 cols each). Grid y = H/(2*HB).

#define HB   16
#define NROW (HB + 6)   // 22 active pipeline iterations (loop padded to 24)
#define NT   256

#define STEP(TT, S0, S1, S2) do {                                              \
    const int Tt = (TT);                                                       \
    /* residual u (band-row Tt-3, slot S0) BEFORE L overwrites it */           \
    const float ur0 = ucen[S0][0], ur1 = ucen[S0][1],                          \
                ur2 = ucen[S0][2], ur3 = ucen[S0][3];                          \
    if (Tt < NROW) {                                                           \
        /* ---- L(Tt): u band-row Tt, abs gy = gy0+Tt-3 ---- */                \
        const int gy = gy0 + Tt - 3;                                           \
        float* w = uw[S0];                                                     \
        if ((unsigned)gy < (unsigned)H) {                                      \
            const float* row = uc + (long)gy * W;                              \
            const float4 va = *(const float4*)(row + ca);                      \
            const float4 vb = *(const float4*)(row + c0);                      \
            const float4 vc = *(const float4*)(row + cc);                      \
            w[0] = inb0  ? va.x : 0.f;  w[1]  = inb1  ? va.y : 0.f;            \
            w[2] = inb2  ? va.z : 0.f;  w[3]  = inb3  ? va.w : 0.f;            \
            w[4] = vb.x;                w[5]  = vb.y;                          \
            w[6] = vb.z;                w[7]  = vb.w;                          \
            w[8] = inb8  ? vc.x : 0.f;  w[9]  = inb9  ? vc.y : 0.f;            \
            w[10] = inb10 ? vc.z : 0.f; w[11] = inb11 ? vc.w : 0.f;            \
        } else {                                                               \
            _Pragma("unroll") for (int i = 0; i < 12; ++i) w[i] = 0.f;         \
        }                                                                      \
        ucen[S0][0] = w[4]; ucen[S0][1] = w[5];                                \
        ucen[S0][2] = w[6]; ucen[S0][3] = w[7];                                \
    }                                                                          \
    if (Tt >= 2 && Tt < NROW) {                                                \
        /* ---- UX(Tt): ux/uy band-row Tt-1, abs gy = gy0+Tt-4 ---- */         \
        float* xr = xw[S2]; float* yr = yw[S2];                                \
        const int gy = gy0 + Tt - 4;                                           \
        if ((unsigned)gy < (unsigned)H) {                                      \
            const float* a = uw[S1];   /* row Tt-2 */                          \
            const float* m = uw[S2];   /* row Tt-1 */                          \
            const float* b = uw[S0];   /* row Tt   */                          \
            _Pragma("unroll") for (int c = 0; c < 8; ++c) {                    \
                const float A = a[c+1], B = a[c+2], C = a[c+3];                \
                const float D = m[c+1],             E = m[c+3];                \
                const float F = b[c+1], Gg = b[c+2], Hh = b[c+3];              \
                const float x = (C - A) + 2.f*(E - D) + (Hh - F);              \
                const float y = (F + 2.f*Gg + Hh) - (A + 2.f*B + C);           \
                xr[c] = mU[c+2] ? x : 0.f;                                     \
                yr[c] = mU[c+2] ? y : 0.f;                                     \
            }                                                                  \
        } else {                                                               \
            _Pragma("unroll") for (int c = 0; c < 8; ++c) { xr[c]=0.f; yr[c]=0.f; } \
        }                                                                      \
    }                                                                          \
    if (Tt >= 4 && Tt < NROW) {                                                \
        /* ---- PQ(Tt): P band-row Tt-2, abs gy = gy0+Tt-5 ---- */             \
        float* dp = dP[S1]; float* eq = eQ[S1];                                \
        const int gy = gy0 + Tt - 5;                                           \
        if ((unsigned)gy < (unsigned)H) {                                      \
            const float* xt = xw[S0];  /* ux row Tt-3 */                       \
            const float* xm = xw[S1];  /* ux row Tt-2 */                       \
            const float* xb = xw[S2];  /* ux row Tt-1 */                       \
            const float* yt = yw[S0];                                          \
            const float* ym = yw[S1];                                          \
            const float* yb = yw[S2];                                          \
            float P[6], Q[6];                                                  \
            _Pragma("unroll") for (int c = 0; c < 6; ++c) {                    \
                const float xc = xm[c+1], yc = ym[c+1];                        \
                const float uxx = (xt[c+2]-xt[c]) + 2.f*(xm[c+2]-xm[c])        \
                                + (xb[c+2]-xb[c]);                             \
                const float uxy = (xb[c] + 2.f*xb[c+1] + xb[c+2])              \
                                - (xt[c] + 2.f*xt[c+1] + xt[c+2]);             \
                const float uyy = (yb[c] + 2.f*yb[c+1] + yb[c+2])              \
                                - (yt[c] + 2.f*yt[c+1] + yt[c+2]);             \
                const float den = 1.f + xc*xc + yc*yc;                         \
                const float Gv = (uxx*uyy - uxy*uxy)                           \
                               * __builtin_amdgcn_rcpf(den*den + 1e-6f);       \
                const float phi = __expf(-fabsf(Gv));                          \
                /* xc,yc already 0 at invalid cols; phi finite -> P,Q = 0 */   \
                P[c] = phi * xc;                                               \
                Q[c] = phi * yc;                                               \
            }                                                                  \
            dp[0] = P[2]-P[0]; dp[1] = P[3]-P[1];                              \
            dp[2] = P[4]-P[2]; dp[3] = P[5]-P[3];                              \
            eq[0] = Q[0]+2.f*Q[1]+Q[2]; eq[1] = Q[1]+2.f*Q[2]+Q[3];            \
            eq[2] = Q[2]+2.f*Q[3]+Q[4]; eq[3] = Q[3]+2.f*Q[4]+Q[5];            \
        } else {                                                               \
            _Pragma("unroll") for (int c = 0; c < 4; ++c) { dp[c]=0.f; eq[c]=0.f; } \
        }                                                                      \
    }                                                                          \
    if (Tt >= 6 && Tt < NROW) {                                                \
        /* ---- OUT(Tt): out band-row Tt-3, abs gy = gy0+Tt-6 (in-domain) ---- */ \
        /* P rows: gy-1 -> S2 (w1), gy -> S0 (w2), gy+1 -> S1 (w1) */          \
        const float o0 = ur0 + (dP[S2][0] + 2.f*dP[S0][0] + dP[S1][0])         \
                             + (eQ[S1][0] - eQ[S2][0]);                        \
        const float o1 = ur1 + (dP[S2][1] + 2.f*dP[S0][1] + dP[S1][1])         \
                             + (eQ[S1][1] - eQ[S2][1]);                        \
        const float o2 = ur2 + (dP[S2][2] + 2.f*dP[S0][2] + dP[S1][2])         \
                             + (eQ[S1][2] - eQ[S2][2]);                        \
        const float o3 = ur3 + (dP[S2][3] + 2.f*dP[S0][3] + dP[S1][3])         \
                             + (eQ[S1][3] - eQ[S2][3]);                        \
        *(float4*)(oc + (long)(gy0 + Tt - 6) * W + c0) =                       \
            make_float4(o0, o1, o2, o3);                                       \
    }                                                                          \
} while (0)

__global__ __launch_bounds__(NT) void gcdd_sweep(
    const float* __restrict__ u, float* __restrict__ out, int H, int W)
{
    // ---- De-phasing stagger: class 0..3 -> sleep ~0/256/512/768 cycles.
    // Co-resident blocks start ~1/3-iteration apart so load bursts from one
    // wave overlap compute of another (tests the phase-lock hypothesis).
    {
        const int cls = (int)((blockIdx.z * gridDim.y + blockIdx.y) & 3u);
        if (cls == 1) __builtin_amdgcn_s_sleep(4);
        else if (cls == 2) __builtin_amdgcn_s_sleep(8);
        else if (cls == 3) __builtin_amdgcn_s_sleep(12);
    }

    const int tid   = threadIdx.x;
    const int strip = tid & 127;          // 128 strips x 4 cols = W = 512
    const int band  = tid >> 7;           // 2 bands per block (wave-uniform)
    const int c0    = strip * 4;
    const int gy0   = (blockIdx.y * 2 + band) * HB;
    const long chan = blockIdx.z;
    const float* __restrict__ uc = u + chan * (long)H * W;
    float* __restrict__ oc = out + chan * (long)H * W;

    // Clamped load-base cols (keeps addresses in-bounds; clamped-in values are
    // masked to zero below, implementing the zero-padding of the first conv).
    const int ca = (c0 - 4 < 0) ? 0 : (c0 - 4);
    const int cc = (c0 + 4 > W - 4) ? (W - 4) : (c0 + 4);

    // uw[i] holds u col c0-4+i; validity masks (only edge strips have false).
    bool mU[12];
    #pragma unroll
    for (int i = 0; i < 12; ++i)
        mU[i] = (unsigned)(c0 - 4 + i) < (unsigned)W;
    const bool inb0 = mU[0], inb1 = mU[1], inb2 = mU[2], inb3 = mU[3];
    const bool inb8 = mU[8], inb9 = mU[9], inb10 = mU[10], inb11 = mU[11];

    float uw[3][12];
    float ucen[3][4] = {};
    float xw[3][8], yw[3][8];
    float dP[3][4], eQ[3][4];

    // 24 iterations (22 active), 3x-unrolled: all slot indices literal.
    for (int t = 0; t < NROW + 2; t += 3) {
        STEP(t + 0, 0, 1, 2);
        STEP(t + 1, 1, 2, 0);
        STEP(t + 2, 2, 0, 1);
    }
}

extern "C" void kernel_launch(void* const* d_in, const int* in_sizes, int n_in,
                              void* d_out, int out_size, void* d_ws, size_t ws_size,
                              hipStream_t stream) {
    const float* u = (const float*)d_in[0];
    float* out = (float*)d_out;

    const int H = 512, W = 512;
    const int channels = in_sizes[0] / (H * W);  // B*C = 48

    dim3 grid(1, H / (2 * HB), channels);        // 1 x 16 x 48 = 768 blocks
    dim3 block(NT);
    gcdd_sweep<<<grid, block, 0, stream>>>(u, out, H, W);
}